// Round 5
// baseline (437.292 us; speedup 1.0000x reference)
//
#include <hip/hip_runtime.h>

#define N_NODES 20000
#define N_EDGES 8192
#define DIM 128
#define NWORDS 313        // ceil(20000/64) node-words
#define XT_STRIDE 20032   // NWORDS*64, padded node dim for Xt
#define NT_STRIDE 20032   // maskNT row length in u64 (k1 writes all of it)
#define KSPLIT 8
#define WPC 40            // mask words per K-chunk in k2m (7x40 + 33)
#define ZPAD 40           // Zl row stride (ushort) in k2rz bounce

typedef unsigned long long u64;
typedef __attribute__((ext_vector_type(8))) __bf16 bf16x8_t;
typedef __attribute__((ext_vector_type(4))) float f32x4;

__device__ __forceinline__ f32x4 mfma16(bf16x8_t a, bf16x8_t b, f32x4 c) {
  return __builtin_amdgcn_mfma_f32_16x16x32_bf16(a, b, c, 0, 0, 0);
}

// fp32 -> bf16 bits, round-to-nearest-even
__device__ __forceinline__ ushort f2bf(float f) {
  unsigned int x = __float_as_uint(f);
  unsigned int r = (x + 0x7FFFu + ((x >> 16) & 1u)) >> 16;
  return (ushort)r;
}

// expand 8 mask bits -> 8 bf16 values (1.0/0.0)
__device__ __forceinline__ bf16x8_t expand8(unsigned int byte) {
  union { unsigned int u[4]; bf16x8_t v; } A;
  const unsigned int w = byte | (byte << 15);
#pragma unroll
  for (int p = 0; p < 4; ++p) {
    A.u[p] = ((w >> (2 * p)) & 0x00010001u) * 0x3F80u;
  }
  return A.v;
}

#define GLOAD_LDS16(g, l)                                                  \
  __builtin_amdgcn_global_load_lds(                                        \
      (const __attribute__((address_space(1))) void*)(g),                  \
      (__attribute__((address_space(3))) void*)(l), 16, 0, 0)

// ---------------------------------------------------------------------------
// K0: Xt[d][n] = bf16(X[n][d]), n padded to XT_STRIDE with zeros.
// ---------------------------------------------------------------------------
__global__ __launch_bounds__(256) void k0_xt(const float* __restrict__ X,
                                             ushort* __restrict__ Xt) {
  __shared__ float T[64][129];
  const int t = threadIdx.x;
  const int n0 = blockIdx.x * 64;
#pragma unroll
  for (int i = 0; i < 32; ++i) {
    const int flat = i * 256 + t;
    const int nl = flat >> 7, d = flat & 127;
    const int n = n0 + nl;
    T[nl][d] = (n < N_NODES) ? X[(size_t)n * DIM + d] : 0.f;
  }
  __syncthreads();
  const int d = t >> 1, half = t & 1;
#pragma unroll
  for (int g = 0; g < 4; ++g) {
    union { ushort h[8]; int4 v; } u;
#pragma unroll
    for (int j = 0; j < 8; ++j) {
      const int nl = half * 32 + g * 8 + j;
      u.h[j] = f2bf(T[nl][d]);
    }
    *(int4*)&Xt[(size_t)d * XT_STRIDE + n0 + half * 32 + g * 8] = u.v;
  }
}

// ---------------------------------------------------------------------------
// K1: stream H once -> maskT[c][e] (bits = nodes), maskNT[ew][n] (bits = edges).
// ---------------------------------------------------------------------------
__global__ __launch_bounds__(256) void k1_mask(const float* __restrict__ H,
                                               u64* __restrict__ maskNT,
                                               u64* __restrict__ maskT) {
  const int tid  = threadIdx.x;
  const int wave = tid >> 6, lane = tid & 63;
  const int e  = blockIdx.x * 256 + wave * 64 + lane;
  const int n0 = blockIdx.y * 64;
  const int ew = blockIdx.x * 4 + wave;   // edge-window index 0..127

  u64 tmask = 0;
#pragma unroll 8
  for (int i = 0; i < 64; ++i) {
    const int n = n0 + i;
    const bool pred = (n < N_NODES) && (H[(size_t)n * N_EDGES + e] != 0.0f);
    const u64 bal = __ballot(pred);
    if (lane == 0) maskNT[(size_t)ew * NT_STRIDE + n] = bal;
    tmask |= pred ? (1ull << i) : 0ull;
  }
  maskT[(size_t)blockIdx.y * N_EDGES + e] = tmask;
}

// ---------------------------------------------------------------------------
// K_deg: DeInv[e], DvInv[n] from mask popcounts. Deterministic, no atomics.
// ---------------------------------------------------------------------------
__global__ __launch_bounds__(256) void k_deg(const u64* __restrict__ maskT,
                                             const u64* __restrict__ maskNT,
                                             float* __restrict__ DeInv,
                                             float* __restrict__ DvInv) {
  const int t = blockIdx.x * 256 + threadIdx.x;
  if (t < N_EDGES) {
    int s = 0;
    for (int c = 0; c < NWORDS; ++c) s += __popcll(maskT[(size_t)c * N_EDGES + t]);
    DeInv[t] = s ? (1.0f / (float)s) : 0.0f;
  } else if (t < N_EDGES + N_NODES) {
    const int n = t - N_EDGES;
    int s = 0;
    for (int ew = 0; ew < 128; ++ew) s += __popcll(maskNT[(size_t)ew * NT_STRIDE + n]);
    DvInv[n] = s ? (1.0f / (float)s) : 0.0f;
  }
}

// ---------------------------------------------------------------------------
// K2m: Mp[p][e][d] partial of (H^T X). 512 blocks = 64 e-tiles x 8 K-chunks.
// 2x2 wave grid, wave tile 64x64 (m=4, fn=4): each B-frag feeds 4 MFMA.
// ---------------------------------------------------------------------------
__global__ __launch_bounds__(256, 2) void k2m(const u64* __restrict__ maskT,
                                              const ushort* __restrict__ Xt,
                                              float* __restrict__ Mp) {
  __shared__ __align__(16) char lds[2][16384];
  const int t = threadIdx.x, lane = t & 63, w = t >> 6;
  const int wr = w >> 1, wc = w & 1;
  const int bid = blockIdx.x;
  const int p  = bid >> 6;
  const int eb = (bid & 63) * 128;
  const int w0 = p * WPC;
  const int nsteps = min(WPC, NWORDS - w0);
  const int l15 = lane & 15, lh = lane >> 4;

  f32x4 acc[4][4];
#pragma unroll
  for (int m = 0; m < 4; ++m)
#pragma unroll
    for (int n = 0; n < 4; ++n) acc[m][n] = (f32x4){0.f, 0.f, 0.f, 0.f};

  auto stage = [&](int buf, int ks) {
#pragma unroll
    for (int i = 0; i < 4; ++i) {
      const int flat = i * 256 + t;
      const int d = flat >> 3, sp = flat & 7;
      const int s = sp ^ (d & 7);                 // inverse-swizzled source
      const ushort* src = Xt + (size_t)d * XT_STRIDE + (w0 + ks) * 64 + s * 8;
      GLOAD_LDS16(src, &lds[buf][(i * 256 + w * 64) * 16]);
    }
  };
  auto loadwords = [&](u64* wd, int ks) {
#pragma unroll
    for (int m = 0; m < 4; ++m)
      wd[m] = maskT[(size_t)(w0 + ks) * N_EDGES + eb + wr * 64 + m * 16 + l15];
  };

  u64 wcur[4], wnxt[4];
  stage(0, 0);
  loadwords(wcur, 0);
  __syncthreads();

  int buf = 0;
  for (int ks = 0; ks < nsteps; ++ks) {
    const bool pre = (ks + 1 < nsteps);
    if (pre) { stage(buf ^ 1, ks + 1); loadwords(wnxt, ks + 1); }

    bf16x8_t bf[2][4];
#pragma unroll
    for (int kh = 0; kh < 2; ++kh)
#pragma unroll
      for (int fn = 0; fn < 4; ++fn) {
        const int c = wc * 64 + fn * 16 + l15;
        const int s = kh * 4 + lh;
        const int slot = 8 * c + (s ^ (c & 7));   // swizzled read
        bf[kh][fn] = *(const bf16x8_t*)&lds[buf][slot * 16];
      }
#pragma unroll
    for (int m = 0; m < 4; ++m) {
#pragma unroll
      for (int kh = 0; kh < 2; ++kh) {
        const unsigned int half = (unsigned int)(wcur[m] >> (kh * 32));
        const unsigned int byte = (half >> (lh * 8)) & 0xFFu;
        const bf16x8_t a = expand8(byte);
#pragma unroll
        for (int fn = 0; fn < 4; ++fn)
          acc[m][fn] = mfma16(a, bf[kh][fn], acc[m][fn]);
      }
    }
    __syncthreads();
    if (pre) {
#pragma unroll
      for (int m = 0; m < 4; ++m) wcur[m] = wnxt[m];
      buf ^= 1;
    }
  }

#pragma unroll
  for (int m = 0; m < 4; ++m)
#pragma unroll
    for (int fn = 0; fn < 4; ++fn)
#pragma unroll
      for (int r = 0; r < 4; ++r) {
        const int e = eb + wr * 64 + m * 16 + lh * 4 + r;
        const int d = wc * 64 + fn * 16 + l15;
        Mp[((size_t)p * N_EDGES + e) * DIM + d] = acc[m][fn][r];
      }
}

// ---------------------------------------------------------------------------
// K2rz: M-row = (sum_p Mp) * DeInv (bf16);  Z = M @ W^T (MFMA);
//       Zt[o][e] = bf16(Z[e][o]). 256 blocks x 32 e.
// ---------------------------------------------------------------------------
__global__ __launch_bounds__(256) void k2rz(const float* __restrict__ Mp,
                                            const float* __restrict__ DeInv,
                                            const float* __restrict__ W,
                                            ushort* __restrict__ Zt) {
  __shared__ __align__(16) ushort Wb[16384];   // slot(o,sd)=o*16+(sd^(o&7)), 8 ushort
  __shared__ __align__(16) ushort Mb[5120];    // union: A-tile (4096) / Zl[128][ZPAD]
  const int t = threadIdx.x, lane = t & 63, w = t >> 6;
  const int l15 = lane & 15, lh = lane >> 4;
  const int eb = blockIdx.x * 32;

  // stage W as bf16 B-operand (B[k=d][col=o] = W[o][d])
#pragma unroll
  for (int i = 0; i < 8; ++i) {
    const int task = i * 256 + t;
    const int o = task >> 4, sd = task & 15;
    union { ushort h[8]; int4 v; } u;
    const float* src = W + o * DIM + sd * 8;
#pragma unroll
    for (int j = 0; j < 8; ++j) u.h[j] = f2bf(src[j]);
    *(int4*)&Wb[(o * 16 + (sd ^ (o & 7))) * 8] = u.v;
  }
  // reduce Mp partials + DeInv scale -> bf16 A-tile (32 e x 128 d)
#pragma unroll
  for (int i = 0; i < 2; ++i) {
    const int task = i * 256 + t;
    const int el = task >> 4, sd = task & 15;
    const int e = eb + el;
    float s[8] = {0.f, 0.f, 0.f, 0.f, 0.f, 0.f, 0.f, 0.f};
#pragma unroll
    for (int p = 0; p < KSPLIT; ++p) {
      const float* mp = Mp + ((size_t)p * N_EDGES + e) * DIM + sd * 8;
#pragma unroll
      for (int j = 0; j < 8; ++j) s[j] += mp[j];
    }
    const float sc = DeInv[e];
    union { ushort h[8]; int4 v; } u;
#pragma unroll
    for (int j = 0; j < 8; ++j) u.h[j] = f2bf(s[j] * sc);
    *(int4*)&Mb[(el * 16 + (sd ^ (el & 7))) * 8] = u.v;
  }
  __syncthreads();

  // GEMM: wave w -> e-rows (w&1)*16..+16, o-block (w>>1)*64..+64. K=128.
  const int ro = w & 1, oc = w >> 1;
  f32x4 acc[4];
#pragma unroll
  for (int fn = 0; fn < 4; ++fn) acc[fn] = (f32x4){0.f, 0.f, 0.f, 0.f};
  const int el = ro * 16 + l15;
#pragma unroll
  for (int ks = 0; ks < 4; ++ks) {
    const bf16x8_t a = *(const bf16x8_t*)&Mb[(el * 16 + ((ks * 4 + lh) ^ (el & 7))) * 8];
#pragma unroll
    for (int fn = 0; fn < 4; ++fn) {
      const int o = oc * 64 + fn * 16 + l15;
      const bf16x8_t bfr = *(const bf16x8_t*)&Wb[(o * 16 + ((ks * 4 + lh) ^ (o & 7))) * 8];
      acc[fn] = mfma16(a, bfr, acc[fn]);
    }
  }
  __syncthreads();   // all waves done reading Mb A-tile

  // acc -> Zl[o][e_l] (transpose bounce)
#pragma unroll
  for (int fn = 0; fn < 4; ++fn) {
    const int o = oc * 64 + fn * 16 + l15;
#pragma unroll
    for (int r = 0; r < 4; ++r) {
      const int elc = ro * 16 + lh * 4 + r;
      Mb[o * ZPAD + elc] = f2bf(acc[fn][r]);
    }
  }
  __syncthreads();
  // coalesced global write: Zt[o][eb..eb+32)
#pragma unroll
  for (int i = 0; i < 2; ++i) {
    const int task = i * 256 + t;
    const int o = task >> 2, g = task & 3;
    *(int4*)&Zt[(size_t)o * N_EDGES + eb + g * 8] = *(const int4*)&Mb[o * ZPAD + g * 8];
  }
}

// ---------------------------------------------------------------------------
// K3mf: out[n][o] = DvInv[n] * (H Z)[n][o] + b[o]. 313 blocks, BM=64.
// 2x2 wave grid, wave tile 32x64 (m=2, fn=4): each B-frag feeds 2 MFMA.
// ---------------------------------------------------------------------------
__global__ __launch_bounds__(256, 2) void k3mf(const u64* __restrict__ maskNT,
                                               const ushort* __restrict__ Zt,
                                               const float* __restrict__ DvInv,
                                               const float* __restrict__ bias,
                                               float* __restrict__ out) {
  __shared__ __align__(16) char lds[2][16384];
  const int t = threadIdx.x, lane = t & 63, w = t >> 6;
  const int wr = w >> 1, wc = w & 1;
  const int nb = blockIdx.x * 64;
  const int l15 = lane & 15, lh = lane >> 4;

  f32x4 acc[2][4];
#pragma unroll
  for (int m = 0; m < 2; ++m)
#pragma unroll
    for (int fn = 0; fn < 4; ++fn) acc[m][fn] = (f32x4){0.f, 0.f, 0.f, 0.f};

  auto stage = [&](int buf, int ks) {
#pragma unroll
    for (int i = 0; i < 4; ++i) {
      const int flat = i * 256 + t;
      const int o = flat >> 3, sp = flat & 7;
      const int s = sp ^ (o & 7);
      const ushort* src = Zt + (size_t)o * N_EDGES + ks * 64 + s * 8;
      GLOAD_LDS16(src, &lds[buf][(i * 256 + w * 64) * 16]);
    }
  };
  auto loadwords = [&](u64* wd, int ks) {
#pragma unroll
    for (int m = 0; m < 2; ++m)
      wd[m] = maskNT[(size_t)ks * NT_STRIDE + nb + wr * 32 + m * 16 + l15];
  };

  u64 wcur[2], wnxt[2];
  stage(0, 0);
  loadwords(wcur, 0);
  __syncthreads();

  int buf = 0;
  for (int ks = 0; ks < 128; ++ks) {
    const bool pre = (ks + 1 < 128);
    if (pre) { stage(buf ^ 1, ks + 1); loadwords(wnxt, ks + 1); }

    bf16x8_t bf[2][4];
#pragma unroll
    for (int kh = 0; kh < 2; ++kh)
#pragma unroll
      for (int fn = 0; fn < 4; ++fn) {
        const int c = wc * 64 + fn * 16 + l15;
        const int s = kh * 4 + lh;
        const int slot = 8 * c + (s ^ (c & 7));
        bf[kh][fn] = *(const bf16x8_t*)&lds[buf][slot * 16];
      }
#pragma unroll
    for (int m = 0; m < 2; ++m) {
#pragma unroll
      for (int kh = 0; kh < 2; ++kh) {
        const unsigned int half = (unsigned int)(wcur[m] >> (kh * 32));
        const unsigned int byte = (half >> (lh * 8)) & 0xFFu;
        const bf16x8_t a = expand8(byte);
#pragma unroll
        for (int fn = 0; fn < 4; ++fn)
          acc[m][fn] = mfma16(a, bf[kh][fn], acc[m][fn]);
      }
    }
    __syncthreads();
    if (pre) {
      wcur[0] = wnxt[0]; wcur[1] = wnxt[1];
      buf ^= 1;
    }
  }

  float bv[4];
#pragma unroll
  for (int fn = 0; fn < 4; ++fn) bv[fn] = bias[wc * 64 + fn * 16 + l15];
#pragma unroll
  for (int m = 0; m < 2; ++m)
#pragma unroll
    for (int fn = 0; fn < 4; ++fn)
#pragma unroll
      for (int r = 0; r < 4; ++r) {
        const int n = nb + wr * 32 + m * 16 + lh * 4 + r;
        if (n < N_NODES) {
          const int o = wc * 64 + fn * 16 + l15;
          out[(size_t)n * DIM + o] = acc[m][fn][r] * DvInv[n] + bv[fn];
        }
      }
}

// ---------------------------------------------------------------------------
extern "C" void kernel_launch(void* const* d_in, const int* in_sizes, int n_in,
                              void* d_out, int out_size, void* d_ws, size_t ws_size,
                              hipStream_t stream) {
  const float* X = (const float*)d_in[0];
  const float* H = (const float*)d_in[1];
  const float* W = (const float*)d_in[2];
  const float* b = (const float*)d_in[3];
  float* out = (float*)d_out;

  char* ws = (char*)d_ws;
  u64*    maskT  = (u64*)(ws + 0);            // 313*8192*8    = 20,512,768
  u64*    maskNT = (u64*)(ws + 20512768);     // 128*20032*8   = 20,512,768
  ushort* Xt     = (ushort*)(ws + 41025536);  // 128*20032*2   =  5,128,192
  float*  Mp     = (float*)(ws + 46153728);   // 8*8192*128*4  = 33,554,432
  ushort* Zt     = (ushort*)(ws + 79708160);  // 128*8192*2    =  2,097,152
  float*  DeInv  = (float*)(ws + 81805312);   // 32,768
  float*  DvInv  = (float*)(ws + 81838080);   // 80,000 (end ~81.9 MB)

  k0_xt  <<<313, 256, 0, stream>>>(X, Xt);
  k1_mask<<<dim3(32, 313), 256, 0, stream>>>(H, maskNT, maskT);
  k_deg  <<<(N_EDGES + N_NODES + 255) / 256, 256, 0, stream>>>(maskT, maskNT, DeInv, DvInv);
  k2m    <<<512, 256, 0, stream>>>(maskT, Xt, Mp);
  k2rz   <<<256, 256, 0, stream>>>(Mp, DeInv, W, Zt);
  k3mf   <<<313, 256, 0, stream>>>(maskNT, Zt, DvInv, b, out);
}

// Round 6
// 379.629 us; speedup vs baseline: 1.1519x; 1.1519x over previous
//
#include <hip/hip_runtime.h>

#define N_NODES 20000
#define N_EDGES 8192
#define DIM 128
#define NWORDS 313        // ceil(20000/64) node-words
#define XT_STRIDE 20032   // NWORDS*64, padded node dim for Xt
#define NT_STRIDE 20032   // maskNT row length in u64 (k1 writes all of it)
#define KSPLIT 8
#define WPC 40            // mask words per K-chunk in k2m (7x40 + 33)
#define ZPAD 40           // Zl row stride (ushort) in k2rz bounce
#define K3SPLIT 4         // K-chunks in k3p (32 words each)

typedef unsigned long long u64;
typedef __attribute__((ext_vector_type(8))) __bf16 bf16x8_t;
typedef __attribute__((ext_vector_type(4))) float f32x4;

__device__ __forceinline__ f32x4 mfma16(bf16x8_t a, bf16x8_t b, f32x4 c) {
  return __builtin_amdgcn_mfma_f32_16x16x32_bf16(a, b, c, 0, 0, 0);
}

// fp32 -> bf16 bits, round-to-nearest-even
__device__ __forceinline__ ushort f2bf(float f) {
  unsigned int x = __float_as_uint(f);
  unsigned int r = (x + 0x7FFFu + ((x >> 16) & 1u)) >> 16;
  return (ushort)r;
}

// expand 8 mask bits -> 8 bf16 values (1.0/0.0)
__device__ __forceinline__ bf16x8_t expand8(unsigned int byte) {
  union { unsigned int u[4]; bf16x8_t v; } A;
  const unsigned int w = byte | (byte << 15);
#pragma unroll
  for (int p = 0; p < 4; ++p) {
    A.u[p] = ((w >> (2 * p)) & 0x00010001u) * 0x3F80u;
  }
  return A.v;
}

#define GLOAD_LDS16(g, l)                                                  \
  __builtin_amdgcn_global_load_lds(                                        \
      (const __attribute__((address_space(1))) void*)(g),                  \
      (__attribute__((address_space(3))) void*)(l), 16, 0, 0)

// ---------------------------------------------------------------------------
// K0: Xt[d][n] = bf16(X[n][d]), n padded to XT_STRIDE with zeros.
// ---------------------------------------------------------------------------
__global__ __launch_bounds__(256) void k0_xt(const float* __restrict__ X,
                                             ushort* __restrict__ Xt) {
  __shared__ float T[64][129];
  const int t = threadIdx.x;
  const int n0 = blockIdx.x * 64;
#pragma unroll
  for (int i = 0; i < 32; ++i) {
    const int flat = i * 256 + t;
    const int nl = flat >> 7, d = flat & 127;
    const int n = n0 + nl;
    T[nl][d] = (n < N_NODES) ? X[(size_t)n * DIM + d] : 0.f;
  }
  __syncthreads();
  const int d = t >> 1, half = t & 1;
#pragma unroll
  for (int g = 0; g < 4; ++g) {
    union { ushort h[8]; int4 v; } u;
#pragma unroll
    for (int j = 0; j < 8; ++j) {
      const int nl = half * 32 + g * 8 + j;
      u.h[j] = f2bf(T[nl][d]);
    }
    *(int4*)&Xt[(size_t)d * XT_STRIDE + n0 + half * 32 + g * 8] = u.v;
  }
}

// ---------------------------------------------------------------------------
// K1: stream H once -> maskT[c][e], maskNT[ew][n]. Per-lane ballot capture,
// single 512B wave store for maskNT (no exec-masked lane-0 stores).
// ---------------------------------------------------------------------------
__global__ __launch_bounds__(256) void k1_mask(const float* __restrict__ H,
                                               u64* __restrict__ maskNT,
                                               u64* __restrict__ maskT) {
  const int tid  = threadIdx.x;
  const int wave = tid >> 6, lane = tid & 63;
  const int e  = blockIdx.x * 256 + wave * 64 + lane;
  const int n0 = blockIdx.y * 64;
  const int ew = blockIdx.x * 4 + wave;   // edge-window index 0..127

  u64 tmask = 0, myb = 0;
#pragma unroll 8
  for (int i = 0; i < 64; ++i) {
    const int n = n0 + i;
    const bool pred = (n < N_NODES) && (H[(size_t)n * N_EDGES + e] != 0.0f);
    const u64 bal = __ballot(pred);
    myb = (lane == i) ? bal : myb;          // lane i keeps ballot of iter i
    tmask |= pred ? (1ull << i) : 0ull;
  }
  maskNT[(size_t)ew * NT_STRIDE + n0 + lane] = myb;   // 512B coalesced
  maskT[(size_t)blockIdx.y * N_EDGES + e] = tmask;
}

// ---------------------------------------------------------------------------
// K_deg: DeInv / DvInv via 4-way split column popcount + LDS reduce.
// 441 blocks: 128 edge-blocks + 313 node-blocks.
// ---------------------------------------------------------------------------
__global__ __launch_bounds__(256) void k_deg(const u64* __restrict__ maskT,
                                             const u64* __restrict__ maskNT,
                                             float* __restrict__ DeInv,
                                             float* __restrict__ DvInv) {
  __shared__ int red[4][64];
  const int t = threadIdx.x, ol = t & 63, q = t >> 6;
  const int b = blockIdx.x;
  int s = 0;
  if (b < 128) {
    const int e = b * 64 + ol;
    for (int c = q; c < NWORDS; c += 4) s += __popcll(maskT[(size_t)c * N_EDGES + e]);
    red[q][ol] = s;
    __syncthreads();
    if (q == 0) {
      const int tot = red[0][ol] + red[1][ol] + red[2][ol] + red[3][ol];
      DeInv[e] = tot ? (1.0f / (float)tot) : 0.0f;
    }
  } else {
    const int n = (b - 128) * 64 + ol;
    for (int ew = q; ew < 128; ew += 4) s += __popcll(maskNT[(size_t)ew * NT_STRIDE + n]);
    red[q][ol] = s;
    __syncthreads();
    if (q == 0 && n < N_NODES) {
      const int tot = red[0][ol] + red[1][ol] + red[2][ol] + red[3][ol];
      DvInv[n] = tot ? (1.0f / (float)tot) : 0.0f;
    }
  }
}

// ---------------------------------------------------------------------------
// K2m: Mp[p][e][d] partial of (H^T X). 512 blocks = 64 e-tiles x 8 K-chunks.
// 2x2 wave grid, wave tile 64x64 (m=4, fn=4). 2 blocks/CU.
// ---------------------------------------------------------------------------
__global__ __launch_bounds__(256, 2) void k2m(const u64* __restrict__ maskT,
                                              const ushort* __restrict__ Xt,
                                              float* __restrict__ Mp) {
  __shared__ __align__(16) char lds[2][16384];
  const int t = threadIdx.x, lane = t & 63, w = t >> 6;
  const int wr = w >> 1, wc = w & 1;
  const int bid = blockIdx.x;
  const int p  = bid >> 6;
  const int eb = (bid & 63) * 128;
  const int w0 = p * WPC;
  const int nsteps = min(WPC, NWORDS - w0);
  const int l15 = lane & 15, lh = lane >> 4;

  f32x4 acc[4][4];
#pragma unroll
  for (int m = 0; m < 4; ++m)
#pragma unroll
    for (int n = 0; n < 4; ++n) acc[m][n] = (f32x4){0.f, 0.f, 0.f, 0.f};

  auto stage = [&](int buf, int ks) {
#pragma unroll
    for (int i = 0; i < 4; ++i) {
      const int flat = i * 256 + t;
      const int d = flat >> 3, sp = flat & 7;
      const int s = sp ^ (d & 7);                 // inverse-swizzled source
      const ushort* src = Xt + (size_t)d * XT_STRIDE + (w0 + ks) * 64 + s * 8;
      GLOAD_LDS16(src, &lds[buf][(i * 256 + w * 64) * 16]);
    }
  };
  auto loadwords = [&](u64* wd, int ks) {
#pragma unroll
    for (int m = 0; m < 4; ++m)
      wd[m] = maskT[(size_t)(w0 + ks) * N_EDGES + eb + wr * 64 + m * 16 + l15];
  };

  u64 wcur[4], wnxt[4];
  stage(0, 0);
  loadwords(wcur, 0);
  __syncthreads();

  int buf = 0;
  for (int ks = 0; ks < nsteps; ++ks) {
    const bool pre = (ks + 1 < nsteps);
    if (pre) { stage(buf ^ 1, ks + 1); loadwords(wnxt, ks + 1); }

    bf16x8_t bf[2][4];
#pragma unroll
    for (int kh = 0; kh < 2; ++kh)
#pragma unroll
      for (int fn = 0; fn < 4; ++fn) {
        const int c = wc * 64 + fn * 16 + l15;
        const int s = kh * 4 + lh;
        const int slot = 8 * c + (s ^ (c & 7));   // swizzled read
        bf[kh][fn] = *(const bf16x8_t*)&lds[buf][slot * 16];
      }
#pragma unroll
    for (int m = 0; m < 4; ++m) {
#pragma unroll
      for (int kh = 0; kh < 2; ++kh) {
        const unsigned int half = (unsigned int)(wcur[m] >> (kh * 32));
        const unsigned int byte = (half >> (lh * 8)) & 0xFFu;
        const bf16x8_t a = expand8(byte);
#pragma unroll
        for (int fn = 0; fn < 4; ++fn)
          acc[m][fn] = mfma16(a, bf[kh][fn], acc[m][fn]);
      }
    }
    __syncthreads();
    if (pre) {
#pragma unroll
      for (int m = 0; m < 4; ++m) wcur[m] = wnxt[m];
      buf ^= 1;
    }
  }

#pragma unroll
  for (int m = 0; m < 4; ++m)
#pragma unroll
    for (int fn = 0; fn < 4; ++fn)
#pragma unroll
      for (int r = 0; r < 4; ++r) {
        const int e = eb + wr * 64 + m * 16 + lh * 4 + r;
        const int d = wc * 64 + fn * 16 + l15;
        Mp[((size_t)p * N_EDGES + e) * DIM + d] = acc[m][fn][r];
      }
}

// ---------------------------------------------------------------------------
// K2rz: M-row = (sum_p Mp) * DeInv (bf16);  Z = M @ W^T (MFMA);
//       Zt[o][e] = bf16(Z[e][o]). 256 blocks x 32 e.
// ---------------------------------------------------------------------------
__global__ __launch_bounds__(256) void k2rz(const float* __restrict__ Mp,
                                            const float* __restrict__ DeInv,
                                            const float* __restrict__ W,
                                            ushort* __restrict__ Zt) {
  __shared__ __align__(16) ushort Wb[16384];   // slot(o,sd)=o*16+(sd^(o&7)), 8 ushort
  __shared__ __align__(16) ushort Mb[5120];    // union: A-tile (4096) / Zl[128][ZPAD]
  const int t = threadIdx.x, lane = t & 63, w = t >> 6;
  const int l15 = lane & 15, lh = lane >> 4;
  const int eb = blockIdx.x * 32;

  // stage W as bf16 B-operand (B[k=d][col=o] = W[o][d])
#pragma unroll
  for (int i = 0; i < 8; ++i) {
    const int task = i * 256 + t;
    const int o = task >> 4, sd = task & 15;
    union { ushort h[8]; int4 v; } u;
    const float* src = W + o * DIM + sd * 8;
#pragma unroll
    for (int j = 0; j < 8; ++j) u.h[j] = f2bf(src[j]);
    *(int4*)&Wb[(o * 16 + (sd ^ (o & 7))) * 8] = u.v;
  }
  // reduce Mp partials + DeInv scale -> bf16 A-tile (32 e x 128 d), float4 loads
#pragma unroll
  for (int i = 0; i < 2; ++i) {
    const int task = i * 256 + t;
    const int el = task >> 4, sd = task & 15;
    const int e = eb + el;
    float s[8] = {0.f, 0.f, 0.f, 0.f, 0.f, 0.f, 0.f, 0.f};
#pragma unroll
    for (int p = 0; p < KSPLIT; ++p) {
      const float4* mp = (const float4*)(Mp + ((size_t)p * N_EDGES + e) * DIM + sd * 8);
      const float4 a = mp[0], b2 = mp[1];
      s[0] += a.x; s[1] += a.y; s[2] += a.z; s[3] += a.w;
      s[4] += b2.x; s[5] += b2.y; s[6] += b2.z; s[7] += b2.w;
    }
    const float sc = DeInv[e];
    union { ushort h[8]; int4 v; } u;
#pragma unroll
    for (int j = 0; j < 8; ++j) u.h[j] = f2bf(s[j] * sc);
    *(int4*)&Mb[(el * 16 + (sd ^ (el & 7))) * 8] = u.v;
  }
  __syncthreads();

  // GEMM: wave w -> e-rows (w&1)*16..+16, o-block (w>>1)*64..+64. K=128.
  const int ro = w & 1, oc = w >> 1;
  f32x4 acc[4];
#pragma unroll
  for (int fn = 0; fn < 4; ++fn) acc[fn] = (f32x4){0.f, 0.f, 0.f, 0.f};
  const int el = ro * 16 + l15;
#pragma unroll
  for (int ks = 0; ks < 4; ++ks) {
    const bf16x8_t a = *(const bf16x8_t*)&Mb[(el * 16 + ((ks * 4 + lh) ^ (el & 7))) * 8];
#pragma unroll
    for (int fn = 0; fn < 4; ++fn) {
      const int o = oc * 64 + fn * 16 + l15;
      const bf16x8_t bfr = *(const bf16x8_t*)&Wb[(o * 16 + ((ks * 4 + lh) ^ (o & 7))) * 8];
      acc[fn] = mfma16(a, bfr, acc[fn]);
    }
  }
  __syncthreads();   // all waves done reading Mb A-tile

  // acc -> Zl[o][e_l] (transpose bounce)
#pragma unroll
  for (int fn = 0; fn < 4; ++fn) {
    const int o = oc * 64 + fn * 16 + l15;
#pragma unroll
    for (int r = 0; r < 4; ++r) {
      const int elc = ro * 16 + lh * 4 + r;
      Mb[o * ZPAD + elc] = f2bf(acc[fn][r]);
    }
  }
  __syncthreads();
  // coalesced global write: Zt[o][eb..eb+32)
#pragma unroll
  for (int i = 0; i < 2; ++i) {
    const int task = i * 256 + t;
    const int o = task >> 2, g = task & 3;
    *(int4*)&Zt[(size_t)o * N_EDGES + eb + g * 8] = *(const int4*)&Mb[o * ZPAD + g * 8];
  }
}

// ---------------------------------------------------------------------------
// K3p: Yp[p][n][o] partial of (H Z). 1252 blocks = 313 row-tiles x 4 K-chunks
// (32 words each). BM=64, 2x2 waves (wave 32x64, m=2, fn=4). 3 blocks/CU
// co-resident -> cross-block latency hiding of the per-step vmcnt drain.
// ---------------------------------------------------------------------------
__global__ __launch_bounds__(256, 3) void k3p(const u64* __restrict__ maskNT,
                                              const ushort* __restrict__ Zt,
                                              float* __restrict__ Yp) {
  __shared__ __align__(16) char lds[2][16384];
  const int t = threadIdx.x, lane = t & 63, w = t >> 6;
  const int wr = w >> 1, wc = w & 1;
  const int bid = blockIdx.x;
  const int p  = bid & 3;
  const int nb = (bid >> 2) * 64;
  const int kw0 = p * 32;
  const int l15 = lane & 15, lh = lane >> 4;

  f32x4 acc[2][4];
#pragma unroll
  for (int m = 0; m < 2; ++m)
#pragma unroll
    for (int fn = 0; fn < 4; ++fn) acc[m][fn] = (f32x4){0.f, 0.f, 0.f, 0.f};

  auto stage = [&](int buf, int ks) {
#pragma unroll
    for (int i = 0; i < 4; ++i) {
      const int flat = i * 256 + t;
      const int o = flat >> 3, sp = flat & 7;
      const int s = sp ^ (o & 7);
      const ushort* src = Zt + (size_t)o * N_EDGES + (kw0 + ks) * 64 + s * 8;
      GLOAD_LDS16(src, &lds[buf][(i * 256 + w * 64) * 16]);
    }
  };
  auto loadwords = [&](u64* wd, int ks) {
#pragma unroll
    for (int m = 0; m < 2; ++m)
      wd[m] = maskNT[(size_t)(kw0 + ks) * NT_STRIDE + nb + wr * 32 + m * 16 + l15];
  };

  u64 wcur[2], wnxt[2];
  stage(0, 0);
  loadwords(wcur, 0);
  __syncthreads();

  int buf = 0;
  for (int ks = 0; ks < 32; ++ks) {
    const bool pre = (ks + 1 < 32);
    if (pre) { stage(buf ^ 1, ks + 1); loadwords(wnxt, ks + 1); }

    bf16x8_t bf[2][4];
#pragma unroll
    for (int kh = 0; kh < 2; ++kh)
#pragma unroll
      for (int fn = 0; fn < 4; ++fn) {
        const int c = wc * 64 + fn * 16 + l15;
        const int s = kh * 4 + lh;
        const int slot = 8 * c + (s ^ (c & 7));
        bf[kh][fn] = *(const bf16x8_t*)&lds[buf][slot * 16];
      }
#pragma unroll
    for (int m = 0; m < 2; ++m) {
#pragma unroll
      for (int kh = 0; kh < 2; ++kh) {
        const unsigned int half = (unsigned int)(wcur[m] >> (kh * 32));
        const unsigned int byte = (half >> (lh * 8)) & 0xFFu;
        const bf16x8_t a = expand8(byte);
#pragma unroll
        for (int fn = 0; fn < 4; ++fn)
          acc[m][fn] = mfma16(a, bf[kh][fn], acc[m][fn]);
      }
    }
    __syncthreads();
    if (pre) {
      wcur[0] = wnxt[0]; wcur[1] = wnxt[1];
      buf ^= 1;
    }
  }

  // unguarded partial store (rows up to 20031 exist in padded Yp)
#pragma unroll
  for (int m = 0; m < 2; ++m)
#pragma unroll
    for (int fn = 0; fn < 4; ++fn)
#pragma unroll
      for (int r = 0; r < 4; ++r) {
        const int n = nb + wr * 32 + m * 16 + lh * 4 + r;
        const int o = wc * 64 + fn * 16 + l15;
        Yp[((size_t)p * XT_STRIDE + n) * DIM + o] = acc[m][fn][r];
      }
}

// ---------------------------------------------------------------------------
// K3r: out[n][o] = (sum_p Yp[p][n][o]) * DvInv[n] + b[o]. 1250 blocks exact.
// ---------------------------------------------------------------------------
__global__ __launch_bounds__(256) void k3r(const float* __restrict__ Yp,
                                           const float* __restrict__ DvInv,
                                           const float* __restrict__ bias,
                                           float* __restrict__ out) {
  const int task = blockIdx.x * 256 + threadIdx.x;   // < 320000
  const int n = task >> 4;
  const int o0 = (task & 15) * 8;
  float s[8] = {0.f, 0.f, 0.f, 0.f, 0.f, 0.f, 0.f, 0.f};
#pragma unroll
  for (int p = 0; p < K3SPLIT; ++p) {
    const float4* src = (const float4*)(Yp + ((size_t)p * XT_STRIDE + n) * DIM + o0);
    const float4 a = src[0], b2 = src[1];
    s[0] += a.x; s[1] += a.y; s[2] += a.z; s[3] += a.w;
    s[4] += b2.x; s[5] += b2.y; s[6] += b2.z; s[7] += b2.w;
  }
  const float dv = DvInv[n];
  float4 r0, r1;
  const float4 b0 = *(const float4*)(bias + o0);
  const float4 b1 = *(const float4*)(bias + o0 + 4);
  r0.x = s[0] * dv + b0.x; r0.y = s[1] * dv + b0.y;
  r0.z = s[2] * dv + b0.z; r0.w = s[3] * dv + b0.w;
  r1.x = s[4] * dv + b1.x; r1.y = s[5] * dv + b1.y;
  r1.z = s[6] * dv + b1.z; r1.w = s[7] * dv + b1.w;
  float4* dst = (float4*)(out + (size_t)n * DIM + o0);
  dst[0] = r0; dst[1] = r1;
}

// ---------------------------------------------------------------------------
extern "C" void kernel_launch(void* const* d_in, const int* in_sizes, int n_in,
                              void* d_out, int out_size, void* d_ws, size_t ws_size,
                              hipStream_t stream) {
  const float* X = (const float*)d_in[0];
  const float* H = (const float*)d_in[1];
  const float* W = (const float*)d_in[2];
  const float* b = (const float*)d_in[3];
  float* out = (float*)d_out;

  char* ws = (char*)d_ws;
  u64*    maskT  = (u64*)(ws + 0);            // 313*8192*8    = 20,512,768
  u64*    maskNT = (u64*)(ws + 20512768);     // 128*20032*8   = 20,512,768
  ushort* Xt     = (ushort*)(ws + 41025536);  // 128*20032*2   =  5,128,192
  float*  Mp     = (float*)(ws + 46153728);   // 8*8192*128*4  = 33,554,432
  ushort* Zt     = (ushort*)(ws + 79708160);  // 128*8192*2    =  2,097,152
  float*  Yp     = (float*)(ws + 81805312);   // 4*20032*128*4 = 41,025,536
  float*  DeInv  = (float*)(ws + 122830848);  // 32,768
  float*  DvInv  = (float*)(ws + 122863616);  // 80,000 (end ~123 MB)

  k0_xt  <<<313, 256, 0, stream>>>(X, Xt);
  k1_mask<<<dim3(32, 313), 256, 0, stream>>>(H, maskNT, maskT);
  k_deg  <<<441, 256, 0, stream>>>(maskT, maskNT, DeInv, DvInv);
  k2m    <<<512, 256, 0, stream>>>(maskT, Xt, Mp);
  k2rz   <<<256, 256, 0, stream>>>(Mp, DeInv, W, Zt);
  k3p    <<<1252, 256, 0, stream>>>(maskNT, Zt, Yp);
  k3r    <<<1250, 256, 0, stream>>>(Yp, DvInv, b, out);
}